// Round 10
// baseline (138.972 us; speedup 1.0000x reference)
//
#include <hip/hip_runtime.h>

// CRF loss, B=1024, T=512, K=32 — chunked associative scan, FULLY FUSED,
// 16 CHAINS PER SIMD (8 waves x 2 chunks) — max-concurrency experiment.
//
// One WG (512 thr = 8 waves) per sequence. Wave wv owns chunks 2wv, 2wv+1
// (NCH=16, CHL=32), steps interleaved (A,B pairs): 8 independent MFMAs per
// step-pair. Ledger r4-r8: duration pinned at ~62 µs / ~290 cy per
// step-instance across {4,8} waves/SIMD x {1,2} chains/wave (max 8
// chains/SIMD); pipe-time sum ≈ span (near-zero cross-pipe overlap).
// r8 showed ILP substitutes for TLP 1:1 -> concurrency trades linearly.
// This round doubles total chains/SIMD to 16 (8 waves x 2 chains).
//
// r9 post-mortem (infra failure, but code review caught it): the
// "no-transpose" fragment-layout combine computed N^T p, not N p — the
// natural xor-16/32 reduction in fragment layout sums over ROWS. Reverted
// to the PROVEN r8 transpose+combine (p <- N p), re-sequenced to fit
// 1024 dwords/wave: transpose A via stride-20 scratch -> regs, reuse the
// SAME scratch for B (wave-private DS ops are in-order; r8 precedent),
// then dump M^T A -> [0..511], M^T B -> [512..1023].
//
//   * pi-permuted contraction: next step's B-fragment IS the lane's own C
//     fragments -> no LDS/cross-lane in the serial loop.
//   * emit exps staged per 16-step stage into per-wave LDS (2 KB/chunk,
//     4 KB/wave, 32 KB/WG -> 4 WG/CU = 32 waves/CU = 8 waves/SIMD).
//   * step = 4x mfma_16x16x32_bf16 + 2 ds_read_b128 + 16 mul + 8 v_perm;
//     renorm every 8 steps: exact pow2 exponent strip (SALU; no rcp/logf).
//   * VGPR cap 64 at (512,4) — r8's identical step body allocated exactly
//     64. WRITE_SIZE is the spill canary (must stay ~32 B).
//
// Per-wave LDS map (1024 dwords = expAll[wv]):
//   scan      : [0..511] chunk-A exp stage (16x32 f32), [512..1023] chunk-B
//   transpose : scratch [0..639] (stride-20, A then B sequentially)
//   dump      : M^T A -> [0..511], M^T B -> [512..1023] (row*16 + d)
//   sAux      : [0..7] per-wave Slog, [8..15] per-wave path-score

#define K32 32
#define Tt  512
#define NCH 16
#define CHL 32
#define NST 2
#define STL 16

typedef float  float4v __attribute__((ext_vector_type(4)));
typedef short  short8v __attribute__((ext_vector_type(8)));

__device__ inline float bf2f_lo(unsigned d) { return __uint_as_float(d << 16); }
__device__ inline float bf2f_hi(unsigned d) { return __uint_as_float(d & 0xFFFF0000u); }

// pack two f32 -> bf16x2 dword by truncation: low16 = hi16(lo), high16 = hi16(hi)
__device__ inline unsigned pack_trunc(float hi, float lo) {
    return __builtin_amdgcn_perm(__float_as_uint(hi), __float_as_uint(lo), 0x07060302u);
}
// round-to-nearest-even bf16 (one-time constants only)
__device__ inline unsigned short f2bf_rne(float x) {
    unsigned u = __float_as_uint(x);
    return (unsigned short)((u + 0x7FFFu + ((u >> 16) & 1u)) >> 16);
}

union F8 { unsigned u[4]; short8v v; };

__global__ __launch_bounds__(512, 4) void crf_fused(
    const int*   __restrict__ labels,
    const float* __restrict__ y_pred,
    const float* __restrict__ trans,
    const float* __restrict__ mask,
    float*       __restrict__ out)
{
    __shared__ float expAll[8][1024];         // 32 KB -> 4 WG/CU
    __shared__ float sAux[16];

    const int lane = threadIdx.x & 63;
    const int wv   = __builtin_amdgcn_readfirstlane(threadIdx.x >> 6);  // wave-uniform
    const int n    = lane & 15;
    const int q    = lane >> 4;
    const int seq  = blockIdx.x;              // scalar

    float* ebA = &expAll[wv][0];
    float* ebB = ebA + 512;

    const float* yp  = y_pred + (size_t)seq * Tt * K32;
    const int*   lb  = labels + (size_t)seq * Tt;
    const float* mkp = mask   + (size_t)seq * Tt;
    const int tbA = wv * 64;                  // chunk 2wv   (32 steps)
    const int tbB = tbA + 32;                 // chunk 2wv+1 (32 steps)

    // ---- path score + mask ballot (64 lanes <-> this wave's 64 timesteps) ----
    float sc;
    float mlane;
    {
        const int t = tbA + lane;             // covers both chunks
        const int lab0 = lb[t];
        mlane = mkp[t];
        sc = yp[t * K32 + lab0] * mlane;
        if (t < Tt - 1) {
            sc += trans[lab0 * K32 + lb[t + 1]] * (mlane * mkp[t + 1]);
        }
#pragma unroll
        for (int s = 1; s < 64; s <<= 1) sc += __shfl_xor(sc, s, 64);
    }
    unsigned long long mb = __ballot(mlane != 0.0f);
    if (wv == 0) mb &= ~1ull;                 // skip t=0 (alpha0 seeds combine)
    const int applied = __popcll(mb);

    // ---- constant A in pi-k-order ----
    F8 AE0, AE1;
#pragma unroll
    for (int h = 0; h < 4; ++h) {
        const int k0 = (h < 2) ? (q * 4 + 2 * h) : (16 + q * 4 + 2 * (h - 2));
        const int k1 = k0 + 1;
        AE0.u[h] = ((unsigned)f2bf_rne(__expf(trans[k0 * K32 + n]) * 0.03125f)) |
                   (((unsigned)f2bf_rne(__expf(trans[k1 * K32 + n]) * 0.03125f)) << 16);
        AE1.u[h] = ((unsigned)f2bf_rne(__expf(trans[k0 * K32 + 16 + n]) * 0.03125f)) |
                   (((unsigned)f2bf_rne(__expf(trans[k1 * K32 + 16 + n]) * 0.03125f)) << 16);
    }

    // ---- identity B fragments (pi-order) for both chunks ----
    F8 BA0, BA1, BB0, BB1;
#pragma unroll
    for (int h = 0; h < 4; ++h) {
        const int r0 = (h < 2) ? (q * 4 + 2 * h) : (16 + q * 4 + 2 * (h - 2));
        const int r1 = r0 + 1;
        unsigned w0 = 0, w1 = 0;
        if (r0 == n)      w0 |= 0x3F80u;
        if (r1 == n)      w0 |= 0x3F800000u;
        if (r0 == 16 + n) w1 |= 0x3F80u;
        if (r1 == 16 + n) w1 |= 0x3F800000u;
        BA0.u[h] = w0; BA1.u[h] = w1;
        BB0.u[h] = w0; BB1.u[h] = w1;
    }

    const float4v zf = {0.f, 0.f, 0.f, 0.f};  // hoisted MFMA C-in
    int eSum = 0;                             // pow2-renorm exponent sum (both chunks)

    const int svoff0 = q * 4;
    const int svoff1 = 16 + q * 4;

    auto stepone = [&](const float* ebx, F8& B0, F8& B1, int i, bool ren) {
        const float4v sv0 = *(const float4v*)&ebx[i * 32 + svoff0];
        const float4v sv1 = *(const float4v*)&ebx[i * 32 + svoff1];

        float4v c00 = __builtin_amdgcn_mfma_f32_16x16x32_bf16(AE0.v, B0.v, zf, 0, 0, 0);
        float4v c01 = __builtin_amdgcn_mfma_f32_16x16x32_bf16(AE0.v, B1.v, zf, 0, 0, 0);
        float4v c10 = __builtin_amdgcn_mfma_f32_16x16x32_bf16(AE1.v, B0.v, zf, 0, 0, 0);
        float4v c11 = __builtin_amdgcn_mfma_f32_16x16x32_bf16(AE1.v, B1.v, zf, 0, 0, 0);

        c00 *= sv0; c01 *= sv0; c10 *= sv1; c11 *= sv1;

        if (ren) {                            // exact pow2 renorm via exponent strip
            const unsigned cb = __builtin_amdgcn_readfirstlane(__float_as_uint(c00[0]));
            const int e = (int)((cb >> 23) & 255u) - 127;
            const float rs = __uint_as_float((unsigned)(127 - e) << 23);  // 2^-e
            c00 *= rs; c01 *= rs; c10 *= rs; c11 *= rs;
            eSum += e;
        }

        B0.u[0] = pack_trunc(c00[1], c00[0]);
        B0.u[1] = pack_trunc(c00[3], c00[2]);
        B0.u[2] = pack_trunc(c10[1], c10[0]);
        B0.u[3] = pack_trunc(c10[3], c10[2]);
        B1.u[0] = pack_trunc(c01[1], c01[0]);
        B1.u[1] = pack_trunc(c01[3], c01[2]);
        B1.u[2] = pack_trunc(c11[1], c11[0]);
        B1.u[3] = pack_trunc(c11[3], c11[2]);
    };

    for (int st = 0; st < NST; ++st) {
        // ---- exp + stage one 16-step block per chunk (2 KB each) ----
        {
            const float4* gA = (const float4*)(yp + (size_t)(tbA + st * STL) * K32);
            const float4* gB = (const float4*)(yp + (size_t)(tbB + st * STL) * K32);
#pragma unroll
            for (int jj = 0; jj < 2; ++jj) {
                const float4 pA = gA[jj * 64 + lane];
                const float4 pB = gB[jj * 64 + lane];
                float4v eA, eB;
                eA[0] = __expf(pA.x); eA[1] = __expf(pA.y);
                eA[2] = __expf(pA.z); eA[3] = __expf(pA.w);
                eB[0] = __expf(pB.x); eB[1] = __expf(pB.y);
                eB[2] = __expf(pB.z); eB[3] = __expf(pB.w);
                *(float4v*)&ebA[(jj * 64 + lane) * 4] = eA;
                *(float4v*)&ebB[(jj * 64 + lane) * 4] = eB;
            }
        }

        const unsigned mA = (unsigned)(mb >> (st * STL)) & 0xFFFFu;
        const unsigned mB = (unsigned)(mb >> (32 + st * STL)) & 0xFFFFu;

        if (((mA | 1u) == 0xFFFFu) && mB == 0xFFFFu) {
            // fast path (covers all-ones and the wv0/st0 bit-0-cleared case)
            const bool do0 = (mA & 1u) != 0u;
#pragma unroll
            for (int i = 0; i < STL; ++i) {
                const bool ren = (i & 7) == 7;
                if (i > 0 || do0) stepone(ebA, BA0, BA1, i, ren);
                stepone(ebB, BB0, BB1, i, ren);
            }
        } else {
            for (int i = 0; i < STL; ++i) {
                const bool ren = (i & 7) == 7;
                if ((mA >> i) & 1u) stepone(ebA, BA0, BA1, i, ren);
                if ((mB >> i) & 1u) stepone(ebB, BB0, BB1, i, ren);
            }
        }
    }

    // ---- two sequential transposes through shared scratch [0..639] ----
    // (wave-private DS ops execute in order: A-writes, A-reads, B-writes
    //  to SAME addresses, B-reads, then the M^T dump — r8-proven pattern.)
    {
        unsigned* scr = (unsigned*)ebA;           // stride-20 col-major scratch
        unsigned rA[8], rB[8];

        // chunk A
        *(uint2*)&scr[n * 20 + q * 2]            = make_uint2(BA0.u[0], BA0.u[1]);
        *(uint2*)&scr[n * 20 + 8 + q * 2]        = make_uint2(BA0.u[2], BA0.u[3]);
        *(uint2*)&scr[(16 + n) * 20 + q * 2]     = make_uint2(BA1.u[0], BA1.u[1]);
        *(uint2*)&scr[(16 + n) * 20 + 8 + q * 2] = make_uint2(BA1.u[2], BA1.u[3]);
        {
            const unsigned short* Nc = (const unsigned short*)scr;
#pragma unroll
            for (int ii = 0; ii < 8; ++ii) {
                const int idx = ii * 64 + lane;
                const int k = idx >> 4, d = idx & 15;
                rA[ii] = (unsigned)Nc[(2 * d) * 40 + k] |
                         ((unsigned)Nc[(2 * d + 1) * 40 + k] << 16);
            }
        }

        // chunk B (same scratch — reads above precede these writes in order)
        *(uint2*)&scr[n * 20 + q * 2]            = make_uint2(BB0.u[0], BB0.u[1]);
        *(uint2*)&scr[n * 20 + 8 + q * 2]        = make_uint2(BB0.u[2], BB0.u[3]);
        *(uint2*)&scr[(16 + n) * 20 + q * 2]     = make_uint2(BB1.u[0], BB1.u[1]);
        *(uint2*)&scr[(16 + n) * 20 + 8 + q * 2] = make_uint2(BB1.u[2], BB1.u[3]);
        {
            const unsigned short* Nc = (const unsigned short*)scr;
#pragma unroll
            for (int ii = 0; ii < 8; ++ii) {
                const int idx = ii * 64 + lane;
                const int k = idx >> 4, d = idx & 15;
                rB[ii] = (unsigned)Nc[(2 * d) * 40 + k] |
                         ((unsigned)Nc[(2 * d + 1) * 40 + k] << 16);
            }
        }

        // M^T dump: A -> [0..511], B -> [512..1023]  (row*16 + d)
        unsigned* md = (unsigned*)ebA;
#pragma unroll
        for (int ii = 0; ii < 8; ++ii) md[ii * 64 + lane] = rA[ii];
#pragma unroll
        for (int ii = 0; ii < 8; ++ii) md[512 + ii * 64 + lane] = rB[ii];
    }
    if (lane == 0) {
        sAux[wv]     = (float)eSum * 0.693147180559945f + (float)applied * 3.46573590f;
        sAux[8 + wv] = sc;
    }

    __syncthreads();

    // ---------------- combine (wave 0 only): 16 serial matvecs + logsumexp ----------------
    if (wv == 0) {
        const int h = lane >> 5;
        const int j = lane & 31;

        auto mt = [&](int cc) -> const unsigned* {
            return (const unsigned*)&expAll[cc >> 1][0] + ((cc & 1) << 9);
        };

        // rolling 1-chunk register prefetch of M^T row j halves
        uint4 cA = *(const uint4*)&mt(0)[j * 16 + 8 * h];
        uint4 cB = *(const uint4*)&mt(0)[j * 16 + 8 * h + 4];

        const float a0 = yp[j];                // mirrored in both halves
        const float m0 = __shfl(a0, 0, 64);
        float p = __expf(a0 - m0);             // p[j], mirrored
        float S = m0;

        float scs = 0.0f;
#pragma unroll
        for (int w = 0; w < 8; ++w) { S += sAux[w]; scs += sAux[8 + w]; }

        const int cb = h << 4;                 // column base for this half
#pragma unroll
        for (int cc = 0; cc < NCH; ++cc) {
            uint4 nA = {0, 0, 0, 0}, nB = {0, 0, 0, 0};
            if (cc + 1 < NCH) {
                nA = *(const uint4*)&mt(cc + 1)[j * 16 + 8 * h];
                nB = *(const uint4*)&mt(cc + 1)[j * 16 + 8 * h + 4];
            }
            const float cn = __shfl(p, 0, 64); // old p[0] (deferred renorm)
            const unsigned u0 = cA.x, u1 = cA.y, u2 = cA.z, u3 = cA.w;
            const unsigned u4 = cB.x, u5 = cB.y, u6 = cB.z, u7 = cB.w;
            float acc = 0.0f;
            acc = fmaf(__shfl(p, cb +  0, 64), bf2f_lo(u0), acc);
            acc = fmaf(__shfl(p, cb +  1, 64), bf2f_hi(u0), acc);
            acc = fmaf(__shfl(p, cb +  2, 64), bf2f_lo(u1), acc);
            acc = fmaf(__shfl(p, cb +  3, 64), bf2f_hi(u1), acc);
            acc = fmaf(__shfl(p, cb +  4, 64), bf2f_lo(u2), acc);
            acc = fmaf(__shfl(p, cb +  5, 64), bf2f_hi(u2), acc);
            acc = fmaf(__shfl(p, cb +  6, 64), bf2f_lo(u3), acc);
            acc = fmaf(__shfl(p, cb +  7, 64), bf2f_hi(u3), acc);
            acc = fmaf(__shfl(p, cb +  8, 64), bf2f_lo(u4), acc);
            acc = fmaf(__shfl(p, cb +  9, 64), bf2f_hi(u4), acc);
            acc = fmaf(__shfl(p, cb + 10, 64), bf2f_lo(u5), acc);
            acc = fmaf(__shfl(p, cb + 11, 64), bf2f_hi(u5), acc);
            acc = fmaf(__shfl(p, cb + 12, 64), bf2f_lo(u6), acc);
            acc = fmaf(__shfl(p, cb + 13, 64), bf2f_hi(u6), acc);
            acc = fmaf(__shfl(p, cb + 14, 64), bf2f_lo(u7), acc);
            acc = fmaf(__shfl(p, cb + 15, 64), bf2f_hi(u7), acc);
            acc += __shfl_xor(acc, 32, 64);    // combine halves -> full dot, mirrored
            p = acc * (1.0f / cn);
            S += __logf(cn);
            cA = nA; cB = nB;
        }

        float sp = p;
        sp += __shfl_xor(sp,  1, 64);
        sp += __shfl_xor(sp,  2, 64);
        sp += __shfl_xor(sp,  4, 64);
        sp += __shfl_xor(sp,  8, 64);
        sp += __shfl_xor(sp, 16, 64);

        if (lane == 0) {
            out[seq] = S + __logf(sp) - scs;
        }
    }
}

extern "C" void kernel_launch(void* const* d_in, const int* in_sizes, int n_in,
                              void* d_out, int out_size, void* d_ws, size_t ws_size,
                              hipStream_t stream) {
    const int*   labels = (const int*)  d_in[0];
    const float* y_pred = (const float*)d_in[1];
    const float* trans  = (const float*)d_in[2];
    const float* mask   = (const float*)d_in[3];
    float* out = (float*)d_out;

    crf_fused<<<1024, 512, 0, stream>>>(labels, y_pred, trans, mask, out);
}